// Round 1
// baseline (431.329 us; speedup 1.0000x reference)
//
#include <hip/hip_runtime.h>
#include <hip/hip_bf16.h>

#define NPTS 8192
#define NB 4
#define TILE 1024
#define RPB 16   // rows per block
#define RPW 4    // rows per wave
#define NBINS 64
#define BCAP 64

__device__ __forceinline__ float wsum(float v){
#pragma unroll
  for (int o=32;o>0;o>>=1) v += __shfl_xor(v,o,64);
  return v;
}

__device__ __forceinline__ float sqd3(float dx,float dy,float dz){
  return fmaf(dx,dx,fmaf(dy,dy,dz*dz));
}

__global__ void init_ws_k(double* ws){ int t=threadIdx.x; if(t<3) ws[t]=0.0; }

__global__ void fin_k(const double* __restrict__ ws, float* __restrict__ out){
  double knn = ws[0] / (32768.0*32.0);
  double bq  = ws[1] / (32768.0*64.0);
  double dat = ws[2] / 98304.0;
  out[0] = (float)(0.75*dat + 0.25*(0.5*knn + 0.5*bq));
}

__global__ __launch_bounds__(256) void loss_k(
  const float* __restrict__ pc, const float* __restrict__ fl,
  const float* __restrict__ gt, double* __restrict__ ws)
{
  __shared__ float sx[TILE],sy[TILE],sz[TILE],sfx[TILE],sfy[TILE],sfz[TILE];
  __shared__ unsigned hist[RPB][NBINS];
  __shared__ unsigned long long bkey[RPB][BCAP];
  __shared__ float bl1v[RPB][BCAP];

  const int tid=threadIdx.x, lane=tid&63, wv=tid>>6, bid=blockIdx.x;
  const unsigned long long lt=(1ull<<lane)-1ull;
  const float R2=0.5625f, BSC=64.0f/0.5625f;

  // ---- data loss (L1 over pred vs gt) ----
  float dl=0.f;
  for (int e=bid*256+tid; e<NB*NPTS*3; e+=gridDim.x*256) dl+=fabsf(fl[e]-gt[e]);
  dl=wsum(dl);
  if (lane==0 && dl!=0.f) atomicAdd(ws+2,(double)dl);

  const int row0=bid*RPB+wv*RPW;
  const int b=row0/NPTS, i0=row0-b*NPTS;   // 16 | 8192 -> block never straddles batches
  const float* pcb=pc+(size_t)b*NPTS*3;
  const float* flb=fl+(size_t)b*NPTS*3;

  float xi[RPW],yi[RPW],zi[RPW],fxi[RPW],fyi[RPW],fzi[RPW];
  int   cnt[RPW]; float bqa[RPW], f1[RPW];
#pragma unroll
  for (int r=0;r<RPW;r++){
    int i=i0+r;
    xi[r]=pcb[3*i]; yi[r]=pcb[3*i+1]; zi[r]=pcb[3*i+2];
    fxi[r]=flb[3*i]; fyi[r]=flb[3*i+1]; fzi[r]=flb[3*i+2];
    cnt[r]=0; bqa[r]=0.f; f1[r]=0.f;
  }
  { unsigned* hp=&hist[0][0];
    for (int h=tid; h<RPB*NBINS; h+=256) hp[h]=0u; }

  // ---- pass 1: per-row radius histogram + online ball-query ----
  for (int t=0;t<NPTS/TILE;t++){
#pragma unroll
    for (int k=0;k<TILE/256;k++){
      int p=k*256+tid, g=t*TILE+p;
      sx[p]=pcb[3*g]; sy[p]=pcb[3*g+1]; sz[p]=pcb[3*g+2];
      sfx[p]=flb[3*g]; sfy[p]=flb[3*g+1]; sfz[p]=flb[3*g+2];
    }
    __syncthreads();
#pragma unroll
    for (int r=0;r<RPW;r++){
      const int wrow=wv*RPW+r;
#pragma unroll 4
      for (int it=0;it<TILE/64;it++){
        int jl=it*64+lane;
        float sq=sqd3(sx[jl]-xi[r],sy[jl]-yi[r],sz[jl]-zi[r]);
        bool in=sq<R2;
        unsigned long long m=__ballot(in);
        if (in){
          int bin=(int)(sq*BSC); bin=min(bin,63);
          atomicAdd(&hist[wrow][bin],1u);
        }
        if (cnt[r]<64){               // wave-uniform: ball query still collecting
          if (in){
            int p=cnt[r]+__popcll(m&lt);
            if (p<64){
              float l1=fabsf(sfx[jl]-fxi[r])+fabsf(sfy[jl]-fyi[r])+fabsf(sfz[jl]-fzi[r]);
              bqa[r]+=l1;
              if (p==0) f1[r]=l1;     // first in-radius index (ascending order)
            }
          }
        }
        cnt[r]+=__popcll(m);
      }
    }
    __syncthreads();
  }

  // ---- per-row KNN threshold bin from histogram ----
  int bstar[RPW], rneed[RPW];
#pragma unroll
  for (int r=0;r<RPW;r++){
    const int wrow=wv*RPW+r;
    unsigned h=hist[wrow][lane];      // lane == bin (NBINS==64)
    unsigned inc=h;
#pragma unroll
    for (int o=1;o<64;o<<=1){ unsigned y=__shfl_up(inc,o,64); if (lane>=o) inc+=y; }
    int M=__shfl((int)inc,63,64);
    if (M<=32){ bstar[r]=64; rneed[r]=0; }   // take every in-radius candidate
    else {
      unsigned exc=inc-h;
      bool sel=(exc<=32u)&&(inc>32u);        // unique crossing bin
      unsigned long long sm=__ballot(sel);
      int src=__ffsll((unsigned long long)sm)-1;
      bstar[r]=src;
      rneed[r]=__shfl(32-(int)exc,src,64);
    }
  }

  // ---- pass 2: accumulate bins < B*, collect boundary bin ----
  float knn=0.f; int bcnt[RPW]={0,0,0,0};
  for (int t=0;t<NPTS/TILE;t++){
#pragma unroll
    for (int k=0;k<TILE/256;k++){
      int p=k*256+tid, g=t*TILE+p;
      sx[p]=pcb[3*g]; sy[p]=pcb[3*g+1]; sz[p]=pcb[3*g+2];
      sfx[p]=flb[3*g]; sfy[p]=flb[3*g+1]; sfz[p]=flb[3*g+2];
    }
    __syncthreads();
#pragma unroll
    for (int r=0;r<RPW;r++){
      const int wrow=wv*RPW+r;
#pragma unroll 4
      for (int it=0;it<TILE/64;it++){
        int jl=it*64+lane;
        float sq=sqd3(sx[jl]-xi[r],sy[jl]-yi[r],sz[jl]-zi[r]);
        bool in=sq<R2;
        int bin=(int)(sq*BSC); bin=min(bin,63);
        bool keep=in&&(bin<bstar[r]);
        bool isb=in&&(bin==bstar[r]);
        float l1=0.f;
        if (keep||isb)
          l1=fabsf(sfx[jl]-fxi[r])+fabsf(sfy[jl]-fyi[r])+fabsf(sfz[jl]-fzi[r]);
        if (keep) knn+=l1;
        unsigned long long mb=__ballot(isb);
        if (isb){
          int p=bcnt[r]+__popcll(mb&lt);
          if (p<BCAP){
            bkey[wrow][p]=((unsigned long long)__float_as_uint(sq)<<32)|(unsigned)(t*TILE+jl);
            bl1v[wrow][p]=l1;
          }
        }
        bcnt[r]+=__popcll(mb);
      }
    }
    __syncthreads();
  }

  // ---- exact select from boundary bin + finalize ----
#pragma unroll
  for (int r=0;r<RPW;r++){
    const int wrow=wv*RPW+r;
    int L=min(bcnt[r],BCAP);
    unsigned long long mykey=~0ull; float myl1=0.f;
    if (lane<L){ mykey=bkey[wrow][lane]; myl1=bl1v[wrow][lane]; }
    int rank=0;
    for (int u=0;u<L;u++) rank += (bkey[wrow][u]<mykey)?1:0;
    if (lane<L && rank<rneed[r]) knn+=myl1;
  }
  knn=wsum(knn);
  float bqt=0.f;
#pragma unroll
  for (int r=0;r<RPW;r++){
    float s=wsum(bqa[r]);
    float ff=wsum(f1[r]);
    s+=(float)(64-min(cnt[r],64))*ff;   // padding duplicates first in-radius neighbor
    bqt+=s;
  }
  if (lane==0){
    atomicAdd(ws+0,(double)knn);
    atomicAdd(ws+1,(double)bqt);
  }
}

extern "C" void kernel_launch(void* const* d_in, const int* in_sizes, int n_in,
                              void* d_out, int out_size, void* d_ws, size_t ws_size,
                              hipStream_t stream) {
  const float* pc   = (const float*)d_in[0];   // pc_source
  const float* pred = (const float*)d_in[2];   // pred_flow
  const float* gt   = (const float*)d_in[3];   // gt_flow
  double* ws = (double*)d_ws;
  float* out = (float*)d_out;

  hipLaunchKernelGGL(init_ws_k, dim3(1), dim3(64), 0, stream, ws);
  hipLaunchKernelGGL(loss_k, dim3((NB*NPTS)/RPB), dim3(256), 0, stream,
                     pc, pred, gt, ws);
  hipLaunchKernelGGL(fin_k, dim3(1), dim3(1), 0, stream, ws, out);
}

// Round 2
// 244.824 us; speedup vs baseline: 1.7618x; 1.7618x over previous
//
#include <hip/hip_runtime.h>
#include <hip/hip_bf16.h>
#include <hip/hip_fp16.h>

#define NPTS 8192
#define NB 4
#define R2C 0.5625f
#define BSC (64.0f/0.5625f)
#define IBSC (0.5625f/64.0f)
#define RPW 8      // rows per wave
#define WPB 4      // waves per block
#define NGRP 128   // 64-pt groups per batch
#define BCAP 32

typedef unsigned u32;
typedef unsigned long long u64;

__device__ __forceinline__ float wsum(float v){
#pragma unroll
  for (int o=32;o>0;o>>=1) v += __shfl_xor(v,o,64);
  return v;
}
__device__ __forceinline__ float rfl(float v){
  return __int_as_float(__builtin_amdgcn_readfirstlane(__float_as_int(v)));
}
__device__ __forceinline__ int cellof(float x,float y,float z){
  int ix=min(15,max(0,(int)((x+5.f)*1.6f)));
  int iy=min(15,max(0,(int)((y+5.f)*1.6f)));
  int iz=min(15,max(0,(int)((z+5.f)*1.6f)));
  int sx=(ix&1)|((ix&2)<<2)|((ix&4)<<4)|((ix&8)<<6);
  int sy=(iy&1)|((iy&2)<<2)|((iy&4)<<4)|((iy&8)<<6);
  int sz=(iz&1)|((iz&2)<<2)|((iz&4)<<4)|((iz&8)<<6);
  return (sx<<2)|(sy<<1)|sz;
}

__global__ void fin_k(const double* __restrict__ ws, float* __restrict__ out){
  double knn = ws[0] / (32768.0*32.0);
  double bq  = ws[1] / (32768.0*64.0);
  double dat = ws[2] / 98304.0;
  out[0] = (float)(0.75*dat + 0.25*(0.5*knn + 0.5*bq));
}

// ---------------- sort pipeline ----------------
__global__ void zero_k(u32* __restrict__ hist, double* __restrict__ acc){
  int t=blockIdx.x*256+threadIdx.x;
  if (t<NB*4096) hist[t]=0u;
  if (t<3) acc[t]=0.0;
}
__global__ void hist_k(const float* __restrict__ pc, u32* __restrict__ hist){
  int t=blockIdx.x*256+threadIdx.x;
  if (t>=NB*NPTS) return;
  int b=t>>13;
  float x=pc[3*t],y=pc[3*t+1],z=pc[3*t+2];
  atomicAdd(&hist[(b<<12)|cellof(x,y,z)],1u);
}
__global__ void scan_k(u32* __restrict__ hist){
  __shared__ u32 part[256];
  int b=blockIdx.x,t=threadIdx.x;
  u32* h=hist+(b<<12);
  u32 loc[16]; u32 run=0;
#pragma unroll
  for (int k=0;k<16;k++){ u32 v=h[t*16+k]; loc[k]=run; run+=v; }
  part[t]=run; __syncthreads();
  if (t==0){ u32 a=0; for (int i=0;i<256;i++){ u32 v=part[i]; part[i]=a; a+=v; } }
  __syncthreads();
  u32 base=part[t];
#pragma unroll
  for (int k=0;k<16;k++) h[t*16+k]=base+loc[k];
}
__global__ void scat_k(const float* __restrict__ pc, const float* __restrict__ fl,
                       u32* __restrict__ hist, float* __restrict__ srt){
  int t=blockIdx.x*256+threadIdx.x;
  if (t>=NB*NPTS) return;
  int b=t>>13;
  float x=pc[3*t],y=pc[3*t+1],z=pc[3*t+2];
  int c=cellof(x,y,z);
  u32 pos=atomicAdd(&hist[(b<<12)|c],1u);
  int d=b*NPTS+(int)pos;
  srt[d]=x; srt[32768+d]=y; srt[65536+d]=z;
  srt[98304+d]=fl[3*t]; srt[131072+d]=fl[3*t+1]; srt[163840+d]=fl[3*t+2];
}
__global__ void aabb_k(const float* __restrict__ srt, unsigned short* __restrict__ ab){
  int t=blockIdx.x*256+threadIdx.x;
  int w=t>>6, lane=t&63;            // 512 waves
  int j=(w>>7)*NPTS+(w&127)*64+lane;
  float x=srt[j],y=srt[32768+j],z=srt[65536+j];
  float x0=x,x1=x,y0=y,y1=y,z0=z,z1=z;
#pragma unroll
  for (int o=32;o>0;o>>=1){
    x0=fminf(x0,__shfl_xor(x0,o,64)); x1=fmaxf(x1,__shfl_xor(x1,o,64));
    y0=fminf(y0,__shfl_xor(y0,o,64)); y1=fmaxf(y1,__shfl_xor(y1,o,64));
    z0=fminf(z0,__shfl_xor(z0,o,64)); z1=fmaxf(z1,__shfl_xor(z1,o,64));
  }
  if (lane==0){
    unsigned short* p=ab+w*6;
    p[0]=__half_as_ushort(__float2half_rd(x0));
    p[1]=__half_as_ushort(__float2half_ru(x1));
    p[2]=__half_as_ushort(__float2half_rd(y0));
    p[3]=__half_as_ushort(__float2half_ru(y1));
    p[4]=__half_as_ushort(__float2half_rd(z0));
    p[5]=__half_as_ushort(__float2half_ru(z1));
  }
}

// ---------------- main loss kernel ----------------
__global__ __launch_bounds__(256) void main_k(
  const float* __restrict__ fl, const float* __restrict__ gt,
  const float* __restrict__ srt, const unsigned short* __restrict__ ab,
  double* __restrict__ ws)
{
  __shared__ u32  hist[WPB][RPW][64];
  __shared__ u64  bkey[WPB][RPW][BCAP];
  __shared__ float bl1[WPB][RPW][BCAP];
  __shared__ u32  glg[WPB][NGRP];
  __shared__ float gld[WPB][NGRP];
  __shared__ unsigned short sab[NGRP*6];

  const int tid=threadIdx.x, lane=tid&63, wv=tid>>6, bid=blockIdx.x;
  const u64 lt=(1ull<<lane)-1ull;

  // data loss
  float dl=0.f;
  for (int e=bid*256+tid; e<NB*NPTS*3; e+=gridDim.x*256) dl+=fabsf(fl[e]-gt[e]);
  dl=wsum(dl);
  if (lane==0 && dl!=0.f) atomicAdd(ws+2,(double)dl);

  const int row0=(bid*WPB+wv)*RPW;
  const int b=row0>>13, i0=row0&(NPTS-1);
  const float* xs=srt+b*NPTS;        const float* ys=srt+32768+b*NPTS;
  const float* zs=srt+65536+b*NPTS;  const float* fx=srt+98304+b*NPTS;
  const float* fy=srt+131072+b*NPTS; const float* fz=srt+163840+b*NPTS;

  { const u32* s=(const u32*)(ab+b*NGRP*6);
    u32* d=(u32*)sab;
    for (int k=tid;k<NGRP*6/2;k+=256) d[k]=s[k]; }
#pragma unroll
  for (int r=0;r<RPW;r++) hist[wv][r][lane]=0u;
  __syncthreads();

  float rx[RPW],ry[RPW],rz[RPW],rfx[RPW],rfy[RPW],rfz[RPW];
#pragma unroll
  for (int r=0;r<RPW;r++){
    rx[r]=rfl(xs[i0+r]); ry[r]=rfl(ys[i0+r]); rz[r]=rfl(zs[i0+r]);
    rfx[r]=rfl(fx[i0+r]); rfy[r]=rfl(fy[i0+r]); rfz[r]=rfl(fz[i0+r]);
  }
  float wx0=rx[0],wx1=rx[0],wy0=ry[0],wy1=ry[0],wz0=rz[0],wz1=rz[0];
#pragma unroll
  for (int r=1;r<RPW;r++){
    wx0=fminf(wx0,rx[r]); wx1=fmaxf(wx1,rx[r]);
    wy0=fminf(wy0,ry[r]); wy1=fmaxf(wy1,ry[r]);
    wz0=fminf(wz0,rz[r]); wz1=fmaxf(wz1,rz[r]);
  }

  // ---- pass 1: histogram + online ball query over surviving groups ----
  int cnt[RPW]; float f1[RPW]; float bqa=0.f;
#pragma unroll
  for (int r=0;r<RPW;r++){ cnt[r]=0; f1[r]=0.f; }
  int nsur=0;

  for (int g=0;g<NGRP;g++){
    const unsigned short* a=&sab[g*6];
    float gx0=__half2float(__ushort_as_half(a[0])), gx1=__half2float(__ushort_as_half(a[1]));
    float gy0=__half2float(__ushort_as_half(a[2])), gy1=__half2float(__ushort_as_half(a[3]));
    float gz0=__half2float(__ushort_as_half(a[4])), gz1=__half2float(__ushort_as_half(a[5]));
    float dxm=fmaxf(0.f,fmaxf(gx0-wx1,wx0-gx1));
    float dym=fmaxf(0.f,fmaxf(gy0-wy1,wy0-gy1));
    float dzm=fmaxf(0.f,fmaxf(gz0-wz1,wz0-gz1));
    float d2=fmaf(dxm,dxm,fmaf(dym,dym,dzm*dzm));
    if (d2>=R2C) continue;
    if (lane==0){ glg[wv][nsur]=(u32)g; gld[wv][nsur]=d2; }
    nsur++;
    int jb=g*64+lane;
    float jx=xs[jb],jy=ys[jb],jz=zs[jb];
    bool collecting=false;
#pragma unroll
    for (int r=0;r<RPW;r++) collecting = collecting || (cnt[r]<64);
    float jfx=0.f,jfy=0.f,jfz=0.f;
    if (collecting){ jfx=fx[jb]; jfy=fy[jb]; jfz=fz[jb]; }
#pragma unroll
    for (int r=0;r<RPW;r++){
      float dx=rx[r]-jx, dy=ry[r]-jy, dz=rz[r]-jz;
      float sq=fmaf(dx,dx,fmaf(dy,dy,dz*dz));
      bool in=sq<R2C;
      u64 m=__ballot(in);
      if (m){
        if (in){
          int bin=min((int)(sq*BSC),63);
          atomicAdd(&hist[wv][r][bin],1u);
        }
        if (cnt[r]<64){
          if (in){
            int p=cnt[r]+__popcll(m&lt);
            if (p<64){
              float l1=fabsf(jfx-rfx[r])+fabsf(jfy-rfy[r])+fabsf(jfz-rfz[r]);
              bqa+=l1;
              if (p==0) f1[r]=l1;
            }
          }
        }
        cnt[r]+=__popcll(m);
      }
    }
  }

  // ---- per-row KNN boundary bin ----
  int bstar[RPW],rneed[RPW];
#pragma unroll
  for (int r=0;r<RPW;r++){
    u32 h=hist[wv][r][lane];
    u32 inc=h;
#pragma unroll
    for (int o=1;o<64;o<<=1){ u32 y=__shfl_up(inc,o,64); if (lane>=o) inc+=y; }
    int M=__shfl((int)inc,63,64);
    if (M<=32){ bstar[r]=64; rneed[r]=0; }
    else{
      u32 exc=inc-h;
      bool sel=(exc<=32u)&&(inc>32u);
      u64 sm=__ballot(sel);
      int src=__ffsll(sm)-1;
      bstar[r]=src;
      rneed[r]=__shfl(32-(int)exc,src,64);
    }
  }
  int mb=0;
#pragma unroll
  for (int r=0;r<RPW;r++) mb=max(mb,bstar[r]);
  float thr2=fminf(R2C,(float)(mb+1)*IBSC);

  // ---- pass 2: accumulate keeps + boundary collect (tighter radius) ----
  float knn=0.f; int bcnt[RPW];
#pragma unroll
  for (int r=0;r<RPW;r++) bcnt[r]=0;
  for (int s=0;s<nsur;s++){
    int g=(int)glg[wv][s]; float d2=gld[wv][s];
    if (d2>=thr2) continue;
    int jb=g*64+lane;
    float jx=xs[jb],jy=ys[jb],jz=zs[jb];
    float jfx=fx[jb],jfy=fy[jb],jfz=fz[jb];
#pragma unroll
    for (int r=0;r<RPW;r++){
      float dx=rx[r]-jx, dy=ry[r]-jy, dz=rz[r]-jz;
      float sq=fmaf(dx,dx,fmaf(dy,dy,dz*dz));
      bool in=sq<R2C;
      int bin=min((int)(sq*BSC),63);
      bool keep=in&&(bin<bstar[r]);
      bool isb=in&&(bin==bstar[r]);
      float l1=0.f;
      if (keep||isb)
        l1=fabsf(jfx-rfx[r])+fabsf(jfy-rfy[r])+fabsf(jfz-rfz[r]);
      if (keep) knn+=l1;
      u64 mbm=__ballot(isb);
      if (mbm){
        if (isb){
          int p=bcnt[r]+__popcll(mbm&lt);
          if (p<BCAP){
            bkey[wv][r][p]=((u64)__float_as_uint(sq)<<32)|(u32)jb;
            bl1[wv][r][p]=l1;
          }
        }
        bcnt[r]+=__popcll(mbm);
      }
    }
  }

  // ---- boundary exact select + finalize ----
#pragma unroll
  for (int r=0;r<RPW;r++){
    if (rneed[r]>0){
      int L=min(bcnt[r],BCAP);
      u64 mykey=~0ull; float myl1=0.f;
      if (lane<L){ mykey=bkey[wv][r][lane]; myl1=bl1[wv][r][lane]; }
      int rank=0;
      for (int u=0;u<L;u++) rank += (bkey[wv][r][u]<mykey)?1:0;
      if (lane<L && rank<rneed[r]) knn+=myl1;
    }
  }
  knn=wsum(knn);
  float bqt=wsum(bqa);
#pragma unroll
  for (int r=0;r<RPW;r++){
    float ff=wsum(f1[r]);
    bqt+=(float)(64-min(cnt[r],64))*ff;
  }
  if (lane==0){
    atomicAdd(ws+0,(double)knn);
    atomicAdd(ws+1,(double)bqt);
  }
}

// ---------------- fallback (verified round-1 kernel) ----------------
#define TILE 1024
#define FRPB 16
#define FRPW 4
__global__ void init_ws_k(double* ws){ int t=threadIdx.x; if(t<3) ws[t]=0.0; }
__global__ __launch_bounds__(256) void fb_loss_k(
  const float* __restrict__ pc, const float* __restrict__ fl,
  const float* __restrict__ gt, double* __restrict__ ws)
{
  __shared__ float sx[TILE],sy[TILE],sz[TILE],sfx[TILE],sfy[TILE],sfz[TILE];
  __shared__ unsigned fhist[FRPB][64];
  __shared__ u64 fbkey[FRPB][64];
  __shared__ float fbl1v[FRPB][64];
  const int tid=threadIdx.x, lane=tid&63, wv=tid>>6, bid=blockIdx.x;
  const u64 lt=(1ull<<lane)-1ull;
  float dl=0.f;
  for (int e=bid*256+tid; e<NB*NPTS*3; e+=gridDim.x*256) dl+=fabsf(fl[e]-gt[e]);
  dl=wsum(dl);
  if (lane==0 && dl!=0.f) atomicAdd(ws+2,(double)dl);
  const int row0=bid*FRPB+wv*FRPW;
  const int b=row0/NPTS, i0=row0-b*NPTS;
  const float* pcb=pc+(size_t)b*NPTS*3;
  const float* flb=fl+(size_t)b*NPTS*3;
  float xi[FRPW],yi[FRPW],zi[FRPW],fxi[FRPW],fyi[FRPW],fzi[FRPW];
  int cnt[FRPW]; float bqa[FRPW], f1[FRPW];
#pragma unroll
  for (int r=0;r<FRPW;r++){
    int i=i0+r;
    xi[r]=pcb[3*i]; yi[r]=pcb[3*i+1]; zi[r]=pcb[3*i+2];
    fxi[r]=flb[3*i]; fyi[r]=flb[3*i+1]; fzi[r]=flb[3*i+2];
    cnt[r]=0; bqa[r]=0.f; f1[r]=0.f;
  }
  { unsigned* hp=&fhist[0][0];
    for (int h=tid; h<FRPB*64; h+=256) hp[h]=0u; }
  for (int t=0;t<NPTS/TILE;t++){
#pragma unroll
    for (int k=0;k<TILE/256;k++){
      int p=k*256+tid, g=t*TILE+p;
      sx[p]=pcb[3*g]; sy[p]=pcb[3*g+1]; sz[p]=pcb[3*g+2];
      sfx[p]=flb[3*g]; sfy[p]=flb[3*g+1]; sfz[p]=flb[3*g+2];
    }
    __syncthreads();
#pragma unroll
    for (int r=0;r<FRPW;r++){
      const int wrow=wv*FRPW+r;
#pragma unroll 4
      for (int it=0;it<TILE/64;it++){
        int jl=it*64+lane;
        float dx=sx[jl]-xi[r],dy=sy[jl]-yi[r],dz=sz[jl]-zi[r];
        float sq=fmaf(dx,dx,fmaf(dy,dy,dz*dz));
        bool in=sq<R2C;
        u64 m=__ballot(in);
        if (in){ int bin=min((int)(sq*BSC),63); atomicAdd(&fhist[wrow][bin],1u); }
        if (cnt[r]<64){
          if (in){
            int p=cnt[r]+__popcll(m&lt);
            if (p<64){
              float l1=fabsf(sfx[jl]-fxi[r])+fabsf(sfy[jl]-fyi[r])+fabsf(sfz[jl]-fzi[r]);
              bqa[r]+=l1;
              if (p==0) f1[r]=l1;
            }
          }
        }
        cnt[r]+=__popcll(m);
      }
    }
    __syncthreads();
  }
  int bstar[FRPW],rneed[FRPW];
#pragma unroll
  for (int r=0;r<FRPW;r++){
    const int wrow=wv*FRPW+r;
    unsigned h=fhist[wrow][lane];
    unsigned inc=h;
#pragma unroll
    for (int o=1;o<64;o<<=1){ unsigned y=__shfl_up(inc,o,64); if (lane>=o) inc+=y; }
    int M=__shfl((int)inc,63,64);
    if (M<=32){ bstar[r]=64; rneed[r]=0; }
    else{
      unsigned exc=inc-h;
      bool sel=(exc<=32u)&&(inc>32u);
      u64 sm=__ballot(sel);
      int src=__ffsll(sm)-1;
      bstar[r]=src;
      rneed[r]=__shfl(32-(int)exc,src,64);
    }
  }
  float knn=0.f; int bcnt[FRPW]={0,0,0,0};
  for (int t=0;t<NPTS/TILE;t++){
#pragma unroll
    for (int k=0;k<TILE/256;k++){
      int p=k*256+tid, g=t*TILE+p;
      sx[p]=pcb[3*g]; sy[p]=pcb[3*g+1]; sz[p]=pcb[3*g+2];
      sfx[p]=flb[3*g]; sfy[p]=flb[3*g+1]; sfz[p]=flb[3*g+2];
    }
    __syncthreads();
#pragma unroll
    for (int r=0;r<FRPW;r++){
      const int wrow=wv*FRPW+r;
#pragma unroll 4
      for (int it=0;it<TILE/64;it++){
        int jl=it*64+lane;
        float dx=sx[jl]-xi[r],dy=sy[jl]-yi[r],dz=sz[jl]-zi[r];
        float sq=fmaf(dx,dx,fmaf(dy,dy,dz*dz));
        bool in=sq<R2C;
        int bin=min((int)(sq*BSC),63);
        bool keep=in&&(bin<bstar[r]);
        bool isb=in&&(bin==bstar[r]);
        float l1=0.f;
        if (keep||isb)
          l1=fabsf(sfx[jl]-fxi[r])+fabsf(sfy[jl]-fyi[r])+fabsf(sfz[jl]-fzi[r]);
        if (keep) knn+=l1;
        u64 mb2=__ballot(isb);
        if (isb){
          int p=bcnt[r]+__popcll(mb2&lt);
          if (p<64){
            fbkey[wrow][p]=((u64)__float_as_uint(sq)<<32)|(unsigned)(t*TILE+jl);
            fbl1v[wrow][p]=l1;
          }
        }
        bcnt[r]+=__popcll(mb2);
      }
    }
    __syncthreads();
  }
#pragma unroll
  for (int r=0;r<FRPW;r++){
    const int wrow=wv*FRPW+r;
    int L=min(bcnt[r],64);
    u64 mykey=~0ull; float myl1=0.f;
    if (lane<L){ mykey=fbkey[wrow][lane]; myl1=fbl1v[wrow][lane]; }
    int rank=0;
    for (int u=0;u<L;u++) rank += (fbkey[wrow][u]<mykey)?1:0;
    if (lane<L && rank<rneed[r]) knn+=myl1;
  }
  knn=wsum(knn);
  float bqt=0.f;
#pragma unroll
  for (int r=0;r<FRPW;r++){
    float s=wsum(bqa[r]);
    float ff=wsum(f1[r]);
    s+=(float)(64-min(cnt[r],64))*ff;
    bqt+=s;
  }
  if (lane==0){
    atomicAdd(ws+0,(double)knn);
    atomicAdd(ws+1,(double)bqt);
  }
}

extern "C" void kernel_launch(void* const* d_in, const int* in_sizes, int n_in,
                              void* d_out, int out_size, void* d_ws, size_t ws_size,
                              hipStream_t stream) {
  (void)in_sizes; (void)n_in; (void)out_size;
  const float* pc = (const float*)d_in[0];   // pc_source
  const float* fl = (const float*)d_in[2];   // pred_flow
  const float* gt = (const float*)d_in[3];   // gt_flow
  float* out = (float*)d_out;
  char* w = (char*)d_ws;
  double* acc = (double*)w;

  const size_t SORT_OFF = 256;
  const size_t AABB_OFF = SORT_OFF + 6u*NB*NPTS*4u;          // 786688
  const size_t HIST_OFF = AABB_OFF + (size_t)NB*NGRP*6*2u;   // 792832
  const size_t NEED     = HIST_OFF + (size_t)NB*4096*4u;     // 858368

  if (ws_size < NEED){
    hipLaunchKernelGGL(init_ws_k, dim3(1), dim3(64), 0, stream, acc);
    hipLaunchKernelGGL(fb_loss_k, dim3((NB*NPTS)/FRPB), dim3(256), 0, stream,
                       pc, fl, gt, acc);
    hipLaunchKernelGGL(fin_k, dim3(1), dim3(1), 0, stream, acc, out);
    return;
  }
  float* srt = (float*)(w+SORT_OFF);
  unsigned short* ab = (unsigned short*)(w+AABB_OFF);
  u32* hist = (u32*)(w+HIST_OFF);

  hipLaunchKernelGGL(zero_k, dim3(64),  dim3(256), 0, stream, hist, acc);
  hipLaunchKernelGGL(hist_k, dim3(128), dim3(256), 0, stream, pc, hist);
  hipLaunchKernelGGL(scan_k, dim3(4),   dim3(256), 0, stream, hist);
  hipLaunchKernelGGL(scat_k, dim3(128), dim3(256), 0, stream, pc, fl, hist, srt);
  hipLaunchKernelGGL(aabb_k, dim3(128), dim3(256), 0, stream, srt, ab);
  hipLaunchKernelGGL(main_k, dim3((NB*NPTS)/(WPB*RPW)), dim3(256), 0, stream,
                     fl, gt, srt, ab, acc);
  hipLaunchKernelGGL(fin_k, dim3(1), dim3(1), 0, stream, acc, out);
}